// Round 1
// baseline (179.943 us; speedup 1.0000x reference)
//
#include <hip/hip_runtime.h>
#include <hip/hip_bf16.h>

#define K_DIM 1024
#define M_DIM 4096
#define N_DIM 8192
#define BK 32
#define PAD 40

typedef __attribute__((ext_vector_type(8))) __bf16 bf16x8_t;
typedef __attribute__((ext_vector_type(4))) float f32x4;
typedef __attribute__((ext_vector_type(4))) int i32x4;

__device__ inline unsigned short f2bf(float f) {
    unsigned u = __float_as_uint(f);
    u += 0x7FFF + ((u >> 16) & 1);   // round-to-nearest-even
    return (unsigned short)(u >> 16);
}

// One block (256 thr) per row: softmax over 1024 cols, write bf16 bits.
__global__ void row_softmax_kernel(const float* __restrict__ w,
                                   unsigned short* __restrict__ o) {
    const int row = blockIdx.x;
    const int tid = threadIdx.x;
    const float4 v = reinterpret_cast<const float4*>(w + (size_t)row * K_DIM)[tid];
    float m = fmaxf(fmaxf(v.x, v.y), fmaxf(v.z, v.w));
    #pragma unroll
    for (int off = 32; off >= 1; off >>= 1) m = fmaxf(m, __shfl_xor(m, off));
    __shared__ float redm[4];
    __shared__ float reds[4];
    if ((tid & 63) == 0) redm[tid >> 6] = m;
    __syncthreads();
    m = fmaxf(fmaxf(redm[0], redm[1]), fmaxf(redm[2], redm[3]));
    const float e0 = __expf(v.x - m), e1 = __expf(v.y - m);
    const float e2 = __expf(v.z - m), e3 = __expf(v.w - m);
    float s = e0 + e1 + e2 + e3;
    #pragma unroll
    for (int off = 32; off >= 1; off >>= 1) s += __shfl_xor(s, off);
    if ((tid & 63) == 0) reds[tid >> 6] = s;
    __syncthreads();
    s = reds[0] + reds[1] + reds[2] + reds[3];
    const float inv = 1.0f / s;
    ushort4 r;
    r.x = f2bf(e0 * inv); r.y = f2bf(e1 * inv);
    r.z = f2bf(e2 * inv); r.w = f2bf(e3 * inv);
    reinterpret_cast<ushort4*>(o + (size_t)row * K_DIM)[tid] = r;
}

// prev (K x N, f32) -> prevT (N x K, bf16) tiled transpose
__global__ void transpose_conv_kernel(const float* __restrict__ src,
                                      unsigned short* __restrict__ dst) {
    __shared__ float t[32][33];
    const int n0 = blockIdx.x * 32;
    const int k0 = blockIdx.y * 32;
    const int tx = threadIdx.x, ty = threadIdx.y;   // 32 x 8
    #pragma unroll
    for (int i = ty; i < 32; i += 8)
        t[i][tx] = src[(size_t)(k0 + i) * N_DIM + n0 + tx];
    __syncthreads();
    #pragma unroll
    for (int i = ty; i < 32; i += 8)
        dst[(size_t)(n0 + i) * K_DIM + k0 + tx] = f2bf(t[tx][i]);
}

// table_weights (16 x 4096): softmax over the 16 entries per column,
// then fold the 15-term combination into 4 coefficients per row.
__global__ void coef_kernel(const float* __restrict__ tw,
                            float4* __restrict__ coef) {
    const int r = blockIdx.x * 256 + threadIdx.x;
    float p[16];
    float m = -1e30f;
    #pragma unroll
    for (int k = 0; k < 16; ++k) { p[k] = tw[k * M_DIM + r]; m = fmaxf(m, p[k]); }
    float s = 0.f;
    #pragma unroll
    for (int k = 0; k < 16; ++k) { p[k] = __expf(p[k] - m); s += p[k]; }
    const float inv = 1.f / s;
    #pragma unroll
    for (int k = 0; k < 16; ++k) p[k] *= inv;
    const float cA  = p[2]+p[3]+p[6]+p[7]-p[8]-p[9]-p[12]-p[13];
    const float cB  = p[4]+p[5]+p[6]+p[7]-p[8]-p[9]-p[10]-p[11];
    const float cAB = p[1]-p[2]-p[4]-2.f*p[6]-p[7]+p[8]+2.f*p[9]+p[11]+p[13]-p[14];
    const float c0  = p[8]+p[9]+p[10]+p[11]+p[12]+p[13]+p[14]+p[15];
    coef[r] = make_float4(cA, cB, cAB, c0);
}

// Fused dual GEMM + epilogue.
// pa, pb: (4096 x 1024) bf16 row-major.  pv: prevT (8192 x 1024) bf16.
// out[r,c] = cA*A + cB*B + cAB*A*B + c0,  A = pa@prev, B = pb@prev.
__global__ __launch_bounds__(256, 2)
void dual_gemm_kernel(const unsigned short* __restrict__ pa,
                      const unsigned short* __restrict__ pb,
                      const unsigned short* __restrict__ pv,
                      const float4* __restrict__ coef,
                      float* __restrict__ out) {
    __shared__ unsigned short sA[128 * PAD];
    __shared__ unsigned short sB[128 * PAD];
    __shared__ unsigned short sP[128 * PAD];

    const int tid = threadIdx.x;
    const int lane = tid & 63;
    const int wid = tid >> 6;
    const int wm = wid >> 1, wn = wid & 1;   // 2x2 wave grid, 64x64 each
    const int bm = blockIdx.y, bn = blockIdx.x;

    f32x4 accA[4][4], accB[4][4];
    const f32x4 z = {0.f, 0.f, 0.f, 0.f};
    #pragma unroll
    for (int i = 0; i < 4; ++i)
        #pragma unroll
        for (int j = 0; j < 4; ++j) { accA[i][j] = z; accB[i][j] = z; }

    const size_t a_base = (size_t)(bm * 128) * K_DIM;
    const size_t p_base = (size_t)(bn * 128) * K_DIM;

    const int frag_row = lane & 15;
    const int frag_k = (lane >> 4) * 8;

    for (int k0 = 0; k0 < K_DIM; k0 += BK) {
        __syncthreads();
        // stage 3 tiles of 128x32 bf16: 512 chunks of 16B each, 2 per thread
        #pragma unroll
        for (int i = 0; i < 2; ++i) {
            const int c = tid + i * 256;
            const int r = c >> 2;
            const int kk = (c & 3) * 8;
            *reinterpret_cast<i32x4*>(&sA[r * PAD + kk]) =
                *reinterpret_cast<const i32x4*>(&pa[a_base + (size_t)r * K_DIM + k0 + kk]);
            *reinterpret_cast<i32x4*>(&sB[r * PAD + kk]) =
                *reinterpret_cast<const i32x4*>(&pb[a_base + (size_t)r * K_DIM + k0 + kk]);
            *reinterpret_cast<i32x4*>(&sP[r * PAD + kk]) =
                *reinterpret_cast<const i32x4*>(&pv[p_base + (size_t)r * K_DIM + k0 + kk]);
        }
        __syncthreads();

        bf16x8_t af[4], bfr[4], pf[4];
        #pragma unroll
        for (int mi = 0; mi < 4; ++mi) {
            const int row = wm * 64 + mi * 16 + frag_row;
            af[mi]  = *reinterpret_cast<const bf16x8_t*>(&sA[row * PAD + frag_k]);
            bfr[mi] = *reinterpret_cast<const bf16x8_t*>(&sB[row * PAD + frag_k]);
        }
        #pragma unroll
        for (int ni = 0; ni < 4; ++ni) {
            const int col = wn * 64 + ni * 16 + frag_row;
            pf[ni] = *reinterpret_cast<const bf16x8_t*>(&sP[col * PAD + frag_k]);
        }
        #pragma unroll
        for (int mi = 0; mi < 4; ++mi)
            #pragma unroll
            for (int ni = 0; ni < 4; ++ni) {
                accA[mi][ni] = __builtin_amdgcn_mfma_f32_16x16x32_bf16(
                    af[mi], pf[ni], accA[mi][ni], 0, 0, 0);
                accB[mi][ni] = __builtin_amdgcn_mfma_f32_16x16x32_bf16(
                    bfr[mi], pf[ni], accB[mi][ni], 0, 0, 0);
            }
    }

    // epilogue: D layout col=lane&15, row=(lane>>4)*4+reg
    const int row_grp = lane >> 4;
    #pragma unroll
    for (int mi = 0; mi < 4; ++mi) {
        #pragma unroll
        for (int ni = 0; ni < 4; ++ni) {
            const int gr0 = bm * 128 + wm * 64 + mi * 16 + row_grp * 4;
            const int gc  = bn * 128 + wn * 64 + ni * 16 + (lane & 15);
            #pragma unroll
            for (int i = 0; i < 4; ++i) {
                const int r = gr0 + i;
                const float4 cf = coef[r];
                const float av = accA[mi][ni][i];
                const float bv = accB[mi][ni][i];
                out[(size_t)r * N_DIM + gc] =
                    fmaf(cf.z, av * bv, fmaf(cf.x, av, fmaf(cf.y, bv, cf.w)));
            }
        }
    }
}

extern "C" void kernel_launch(void* const* d_in, const int* in_sizes, int n_in,
                              void* d_out, int out_size, void* d_ws, size_t ws_size,
                              hipStream_t stream) {
    const float* prev = (const float*)d_in[0];   // (1024, 8192)
    const float* wa   = (const float*)d_in[1];   // (4096, 1024)
    const float* wb   = (const float*)d_in[2];   // (4096, 1024)
    const float* tw   = (const float*)d_in[3];   // (16, 4096)
    float* out = (float*)d_out;                  // (4096, 8192)

    char* ws = (char*)d_ws;
    unsigned short* pa = (unsigned short*)ws;                        // 8 MB
    unsigned short* pb = (unsigned short*)(ws + 8388608);            // 8 MB
    unsigned short* pv = (unsigned short*)(ws + 16777216);           // 16 MB
    float4* coef       = (float4*)(ws + 33554432);                   // 64 KB

    row_softmax_kernel<<<M_DIM, 256, 0, stream>>>(wa, pa);
    row_softmax_kernel<<<M_DIM, 256, 0, stream>>>(wb, pb);
    transpose_conv_kernel<<<dim3(N_DIM / 32, K_DIM / 32), dim3(32, 8), 0, stream>>>(prev, pv);
    coef_kernel<<<M_DIM / 256, 256, 0, stream>>>(tw, coef);
    dual_gemm_kernel<<<dim3(N_DIM / 128, M_DIM / 128), 256, 0, stream>>>(pa, pb, pv, coef, out);
}

// Round 2
// 150.174 us; speedup vs baseline: 1.1982x; 1.1982x over previous
//
#include <hip/hip_runtime.h>
#include <hip/hip_bf16.h>

#define K_DIM 1024
#define M_DIM 4096
#define N_DIM 8192
#define BK 64

typedef __attribute__((ext_vector_type(8))) __bf16 bf16x8_t;
typedef __attribute__((ext_vector_type(4))) float f32x4;

__device__ inline unsigned short f2bf(float f) {
    unsigned u = __float_as_uint(f);
    u += 0x7FFF + ((u >> 16) & 1);   // round-to-nearest-even
    return (unsigned short)(u >> 16);
}

// async global->LDS, 16B per lane. LDS dest must be wave-uniform base;
// lane l writes base + l*16 (m104/m108). Global src is per-lane.
__device__ __forceinline__ void gload_lds16(const void* g, void* l) {
    __builtin_amdgcn_global_load_lds(
        (const __attribute__((address_space(1))) unsigned int*)g,
        (__attribute__((address_space(3))) unsigned int*)l, 16, 0, 0);
}

// One block (256 thr) per row: softmax over 1024 cols, write bf16 bits.
__global__ void row_softmax_kernel(const float* __restrict__ w,
                                   unsigned short* __restrict__ o) {
    const int row = blockIdx.x;
    const int tid = threadIdx.x;
    const float4 v = reinterpret_cast<const float4*>(w + (size_t)row * K_DIM)[tid];
    float m = fmaxf(fmaxf(v.x, v.y), fmaxf(v.z, v.w));
    #pragma unroll
    for (int off = 32; off >= 1; off >>= 1) m = fmaxf(m, __shfl_xor(m, off));
    __shared__ float redm[4];
    __shared__ float reds[4];
    if ((tid & 63) == 0) redm[tid >> 6] = m;
    __syncthreads();
    m = fmaxf(fmaxf(redm[0], redm[1]), fmaxf(redm[2], redm[3]));
    const float e0 = __expf(v.x - m), e1 = __expf(v.y - m);
    const float e2 = __expf(v.z - m), e3 = __expf(v.w - m);
    float s = e0 + e1 + e2 + e3;
    #pragma unroll
    for (int off = 32; off >= 1; off >>= 1) s += __shfl_xor(s, off);
    if ((tid & 63) == 0) reds[tid >> 6] = s;
    __syncthreads();
    s = reds[0] + reds[1] + reds[2] + reds[3];
    const float inv = 1.0f / s;
    ushort4 r;
    r.x = f2bf(e0 * inv); r.y = f2bf(e1 * inv);
    r.z = f2bf(e2 * inv); r.w = f2bf(e3 * inv);
    reinterpret_cast<ushort4*>(o + (size_t)row * K_DIM)[tid] = r;
}

// prev (K x N, f32) -> prevT (N x K, bf16) tiled transpose
__global__ void transpose_conv_kernel(const float* __restrict__ src,
                                      unsigned short* __restrict__ dst) {
    __shared__ float t[32][33];
    const int n0 = blockIdx.x * 32;
    const int k0 = blockIdx.y * 32;
    const int tx = threadIdx.x, ty = threadIdx.y;   // 32 x 8
    #pragma unroll
    for (int i = ty; i < 32; i += 8)
        t[i][tx] = src[(size_t)(k0 + i) * N_DIM + n0 + tx];
    __syncthreads();
    #pragma unroll
    for (int i = ty; i < 32; i += 8)
        dst[(size_t)(n0 + i) * K_DIM + k0 + tx] = f2bf(t[tx][i]);
}

// table_weights (16 x 4096): softmax over 16 entries per column ->
// 4 coefficients per output row: out = cA*A + cB*B + cAB*A*B + c0.
__global__ void coef_kernel(const float* __restrict__ tw,
                            float4* __restrict__ coef) {
    const int r = blockIdx.x * 256 + threadIdx.x;
    float p[16];
    float m = -1e30f;
    #pragma unroll
    for (int k = 0; k < 16; ++k) { p[k] = tw[k * M_DIM + r]; m = fmaxf(m, p[k]); }
    float s = 0.f;
    #pragma unroll
    for (int k = 0; k < 16; ++k) { p[k] = __expf(p[k] - m); s += p[k]; }
    const float inv = 1.f / s;
    #pragma unroll
    for (int k = 0; k < 16; ++k) p[k] *= inv;
    const float cA  = p[2]+p[3]+p[6]+p[7]-p[8]-p[9]-p[12]-p[13];
    const float cB  = p[4]+p[5]+p[6]+p[7]-p[8]-p[9]-p[10]-p[11];
    const float cAB = p[1]-p[2]-p[4]-2.f*p[6]-p[7]+p[8]+2.f*p[9]+p[11]+p[13]-p[14];
    const float c0  = p[8]+p[9]+p[10]+p[11]+p[12]+p[13]+p[14]+p[15];
    coef[r] = make_float4(cA, cB, cAB, c0);
}

// Fused dual GEMM + epilogue. 128x128 tile, BK=64, 4 waves (2x2, 64x64 each).
// LDS linear [128][64] bf16 per tile; swizzle applied on global source +
// ds_read address (rule #21 both-sides): LDS(row, c16) = G(row, c16 ^ (row&7)).
__global__ __launch_bounds__(256, 2)
void dual_gemm_kernel(const unsigned short* __restrict__ pa,
                      const unsigned short* __restrict__ pb,
                      const unsigned short* __restrict__ pv,
                      const float4* __restrict__ coef,
                      float* __restrict__ out) {
    __shared__ unsigned short sA[128 * BK];   // 16 KB
    __shared__ unsigned short sB[128 * BK];
    __shared__ unsigned short sP[128 * BK];

    const int tid = threadIdx.x;
    const int lane = tid & 63;
    const int wid = tid >> 6;
    const int wm = wid >> 1, wn = wid & 1;   // 2x2 wave grid, 64x64 each
    const int bm = blockIdx.y, bn = blockIdx.x;

    f32x4 accA[4][4], accB[4][4];
    const f32x4 z = {0.f, 0.f, 0.f, 0.f};
    #pragma unroll
    for (int i = 0; i < 4; ++i)
        #pragma unroll
        for (int j = 0; j < 4; ++j) { accA[i][j] = z; accB[i][j] = z; }

    // staging geometry: chunk c = wid*4 + j covers LDS bytes [c*1024, +1024)
    // = rows [c*8, c*8+8). lane l -> row c*8 + (l>>3), 16B-col l&7.
    // source 16B-col pre-swizzled: (l&7) ^ (l>>3)  (== (l&7) ^ (row&7)).
    const int sub_row = lane >> 3;                 // 0..7
    const int scol16  = (lane & 7) ^ sub_row;      // swizzled src 16B col

    const int frag_row = lane & 15;
    const int fk16base = lane >> 4;                // 16B col within K row

    for (int k0 = 0; k0 < K_DIM; k0 += BK) {
        __syncthreads();
        #pragma unroll
        for (int j = 0; j < 4; ++j) {
            const int c   = wid * 4 + j;           // 0..15
            const int row = c * 8 + sub_row;       // 0..127
            const size_t goffA = (size_t)(bm * 128 + row) * K_DIM + k0;
            const size_t goffP = (size_t)(bn * 128 + row) * K_DIM + k0;
            const char* gA = (const char*)(pa + goffA) + scol16 * 16;
            const char* gB = (const char*)(pb + goffA) + scol16 * 16;
            const char* gP = (const char*)(pv + goffP) + scol16 * 16;
            char* lA = (char*)sA + c * 1024;
            char* lB = (char*)sB + c * 1024;
            char* lP = (char*)sP + c * 1024;
            gload_lds16(gA, lA);
            gload_lds16(gB, lB);
            gload_lds16(gP, lP);
        }
        __syncthreads();   // compiler drains vmcnt(0) before s_barrier

        #pragma unroll
        for (int kk = 0; kk < 2; ++kk) {
            bf16x8_t af[4], bfr[4], pf[4];
            const int fk16 = fk16base + kk * 4;    // 0..7
            #pragma unroll
            for (int mi = 0; mi < 4; ++mi) {
                const int row  = wm * 64 + mi * 16 + frag_row;
                const int byte = row * 128 + ((fk16 ^ (row & 7)) * 16);
                af[mi]  = *reinterpret_cast<const bf16x8_t*>((const char*)sA + byte);
                bfr[mi] = *reinterpret_cast<const bf16x8_t*>((const char*)sB + byte);
            }
            #pragma unroll
            for (int ni = 0; ni < 4; ++ni) {
                const int col  = wn * 64 + ni * 16 + frag_row;
                const int byte = col * 128 + ((fk16 ^ (col & 7)) * 16);
                pf[ni] = *reinterpret_cast<const bf16x8_t*>((const char*)sP + byte);
            }
            #pragma unroll
            for (int mi = 0; mi < 4; ++mi)
                #pragma unroll
                for (int ni = 0; ni < 4; ++ni) {
                    accA[mi][ni] = __builtin_amdgcn_mfma_f32_16x16x32_bf16(
                        af[mi], pf[ni], accA[mi][ni], 0, 0, 0);
                    accB[mi][ni] = __builtin_amdgcn_mfma_f32_16x16x32_bf16(
                        bfr[mi], pf[ni], accB[mi][ni], 0, 0, 0);
                }
        }
    }

    // epilogue: D layout col=lane&15, row=(lane>>4)*4+reg
    const int row_grp = lane >> 4;
    #pragma unroll
    for (int mi = 0; mi < 4; ++mi) {
        #pragma unroll
        for (int ni = 0; ni < 4; ++ni) {
            const int gr0 = bm * 128 + wm * 64 + mi * 16 + row_grp * 4;
            const int gc  = bn * 128 + wn * 64 + ni * 16 + (lane & 15);
            #pragma unroll
            for (int i = 0; i < 4; ++i) {
                const int r = gr0 + i;
                const float4 cf = coef[r];
                const float av = accA[mi][ni][i];
                const float bv = accB[mi][ni][i];
                out[(size_t)r * N_DIM + gc] =
                    fmaf(cf.z, av * bv, fmaf(cf.x, av, fmaf(cf.y, bv, cf.w)));
            }
        }
    }
}

extern "C" void kernel_launch(void* const* d_in, const int* in_sizes, int n_in,
                              void* d_out, int out_size, void* d_ws, size_t ws_size,
                              hipStream_t stream) {
    const float* prev = (const float*)d_in[0];   // (1024, 8192)
    const float* wa   = (const float*)d_in[1];   // (4096, 1024)
    const float* wb   = (const float*)d_in[2];   // (4096, 1024)
    const float* tw   = (const float*)d_in[3];   // (16, 4096)
    float* out = (float*)d_out;                  // (4096, 8192)

    char* ws = (char*)d_ws;
    unsigned short* pa = (unsigned short*)ws;                        // 8 MB
    unsigned short* pb = (unsigned short*)(ws + 8388608);            // 8 MB
    unsigned short* pv = (unsigned short*)(ws + 16777216);           // 16 MB
    float4* coef       = (float4*)(ws + 33554432);                   // 64 KB

    row_softmax_kernel<<<M_DIM, 256, 0, stream>>>(wa, pa);
    row_softmax_kernel<<<M_DIM, 256, 0, stream>>>(wb, pb);
    transpose_conv_kernel<<<dim3(N_DIM / 32, K_DIM / 32), dim3(32, 8), 0, stream>>>(prev, pv);
    coef_kernel<<<M_DIM / 256, 256, 0, stream>>>(tw, coef);
    dual_gemm_kernel<<<dim3(N_DIM / 128, M_DIM / 128), 256, 0, stream>>>(pa, pb, pv, coef, out);
}